// Round 7
// baseline (167.375 us; speedup 1.0000x reference)
//
#include <hip/hip_runtime.h>
#include <math.h>
#include <stdint.h>

#define NV 50000      // visible nodes
#define NH 5000       // hidden nodes
#define NN 55000      // total nodes
#define NB 128        // batch
#define NG 8          // sub-bin groups (one per XCD, blockIdx&7 heuristic)
#define SUBSLOT 64    // max edges per (bin, group): Poisson(~25.6), P(>=64)~1e-9
#define MAXREC 512    // NG * SUBSLOT upper bound on records per hidden unit

// clang vector types: __builtin_nontemporal_load needs real vector types,
// not HIP_vector_type classes
typedef int   vint4   __attribute__((ext_vector_type(4)));
typedef float vfloat4 __attribute__((ext_vector_type(4)));

// ws layout:
//   bits    : offset 0      , NV*4 u32        = 800000 B (128-bit spin mask per visible node)
//   cursors : offset 800000 , NH*NG u32       = 160000 B (group-major: cursors[g*NH+k])
//   records : offset 960000 , NH*NG*SUBSLOT*8 = 20.48 MB (uint2 {v, bits_of_w}, group-major)

// Pass 1 (fused): blocks [0, packBlocks) bit-pack s; remaining blocks bucket
// edges into XCD-local sub-bins. All read-once streams use nontemporal loads
// so the per-XCD L2 keeps record lines resident until all 8 records arrive
// (write-combining) instead of evicting partial lines (R5: 42MB writes vs
// 8.8MB ideal). Scatter does 16 edges/thread: 12 nt-loads -> 16 independent
// atomics -> 16 stores (4x memory-level parallelism per wave).
__global__ void __launch_bounds__(256) pack_scatter_kernel(
        const int* __restrict__ s, uint32_t* __restrict__ bits,
        const vint4* __restrict__ adj4, const vint4* __restrict__ seg4,
        const vfloat4* __restrict__ quad4,
        uint32_t* __restrict__ cursors, uint2* __restrict__ recs,
        int packBlocks, int E4) {
    int blk = blockIdx.x;
    if (blk < packBlocks) {
        // pack: thread = (v, word g): batches [g*32, g*32+32) of column v
        int tid = blk * 256 + threadIdx.x;
        int v = tid >> 2;
        int g = tid & 3;
        if (v >= NV) return;
        const int* col = s + (size_t)g * 32 * NN + v;
        uint32_t w = 0;
#pragma unroll
        for (int j = 0; j < 32; ++j)
            w |= (uint32_t)(__builtin_nontemporal_load(col + (size_t)j * NN) & 1) << j;
        __builtin_nontemporal_store(w, bits + (size_t)v * 4 + g);
    } else {
        int base = (blk - packBlocks) * 1024 + threadIdx.x;   // E4-chunk index
        const int g = blk & (NG - 1);          // this block's XCD (round-robin heuristic)
        uint32_t* gcur = cursors + (size_t)g * NH;
        uint2* grecs = recs + (size_t)g * NH * SUBSLOT;
        vint4 a[4], sg[4];
        vfloat4 w[4];
        bool ok[4];
#pragma unroll
        for (int j = 0; j < 4; ++j) {
            int t = base + j * 256;
            ok[j] = (t < E4);
            if (ok[j]) {
                a[j]  = __builtin_nontemporal_load(adj4 + t);
                sg[j] = __builtin_nontemporal_load(seg4 + t);
                w[j]  = __builtin_nontemporal_load(quad4 + t);
            }
        }
        uint32_t p[16];
#pragma unroll
        for (int j = 0; j < 4; ++j) {
            if (ok[j]) {
                p[j * 4 + 0] = atomicAdd(&gcur[sg[j].x], 1u);
                p[j * 4 + 1] = atomicAdd(&gcur[sg[j].y], 1u);
                p[j * 4 + 2] = atomicAdd(&gcur[sg[j].z], 1u);
                p[j * 4 + 3] = atomicAdd(&gcur[sg[j].w], 1u);
            }
        }
#pragma unroll
        for (int j = 0; j < 4; ++j) {
            if (ok[j]) {
                if (p[j*4+0] < SUBSLOT) grecs[(size_t)sg[j].x * SUBSLOT + p[j*4+0]] = make_uint2((uint32_t)a[j].x, __float_as_uint(w[j].x));
                if (p[j*4+1] < SUBSLOT) grecs[(size_t)sg[j].y * SUBSLOT + p[j*4+1]] = make_uint2((uint32_t)a[j].y, __float_as_uint(w[j].y));
                if (p[j*4+2] < SUBSLOT) grecs[(size_t)sg[j].z * SUBSLOT + p[j*4+2]] = make_uint2((uint32_t)a[j].z, __float_as_uint(w[j].z));
                if (p[j*4+3] < SUBSLOT) grecs[(size_t)sg[j].w * SUBSLOT + p[j*4+3]] = make_uint2((uint32_t)a[j].w, __float_as_uint(w[j].w));
            }
        }
    }
}

// Pass 2: block = one PAIR of hidden units (k0, k0+1). Stage both units'
// records into LDS (flattened, full-active), then accumulate via broadcast
// ds_read_b128 and write a float2 of adjacent k's. Swizzle: the 8 blocks
// covering each 64B out-line (16 k = 8 pairs) land on one XCD.
__global__ void __launch_bounds__(256) field_tanh_kernel(
        const uint32_t* __restrict__ cursors,
        const uint2* __restrict__ recs,
        const uint4* __restrict__ bits4,
        const float* __restrict__ linear,
        float* __restrict__ out) {
    // 2500 pairs = 8 groups x 313 (last group short); consecutive m -> adjacent pairs
    int g8 = blockIdx.x & 7;
    int m = blockIdx.x >> 3;
    int pair = m + 313 * g8;
    if (pair >= NH / 2) return;
    int k0 = pair * 2;
    int tid = threadIdx.x;

    __shared__ __align__(16) uint32_t rows[2][5][MAXREC];  // [pair][word0..3,w][rec]
    __shared__ float part[2][256];

    int T8s[2];
#pragma unroll
    for (int kk = 0; kk < 2; ++kk) {
        int k = k0 + kk;
        int c[NG], offs[NG], T = 0;
#pragma unroll
        for (int g = 0; g < NG; ++g) {
            int cg = (int)cursors[(size_t)g * NH + k];   // block-uniform -> s_load
            if (cg > SUBSLOT) cg = SUBSLOT;
            c[g] = cg;
            offs[g] = T;
            T += cg;
        }
        int T8 = (T + 7) & ~7;
        T8s[kk] = T8;
        // zero-pad w for tail records (word rows may stay garbage: w=0 kills them)
        for (int i = T + tid; i < T8; i += 256) rows[kk][4][i] = 0u;
        // flattened staging: thread t -> record t of concatenated list
        for (int t = tid; t < T; t += 256) {
            int rem = t, g = 0;
            while (rem >= c[g]) { rem -= c[g]; ++g; }
            uint2 r = recs[((size_t)g * NH + k) * SUBSLOT + rem];
            uint4 mw = bits4[r.x];
            rows[kk][0][t] = mw.x;
            rows[kk][1][t] = mw.y;
            rows[kk][2][t] = mw.z;
            rows[kk][3][t] = mw.w;
            rows[kk][4][t] = r.y;
        }
    }
    __syncthreads();

    // accumulate: 256 threads = 128 batches x 2 record-halves
    int b = tid & 127;
    int grp = tid >> 7;
    const int bsh = b & 31;
    const int widx = b >> 5;
#pragma unroll
    for (int kk = 0; kk < 2; ++kk) {
        const uint32_t* mrow = rows[kk][widx];
        const uint32_t* wrow = rows[kk][4];
        float a0 = 0.f, a1 = 0.f, a2 = 0.f, a3 = 0.f;
        for (int i = grp * 4; i < T8s[kk]; i += 8) {
            uint4 mm = *(const uint4*)(mrow + i);   // broadcast ds_read_b128
            uint4 ww = *(const uint4*)(wrow + i);
            float f0 = __uint_as_float(ww.x);
            float f1 = __uint_as_float(ww.y);
            float f2 = __uint_as_float(ww.z);
            float f3 = __uint_as_float(ww.w);
            a0 += ((mm.x >> bsh) & 1u) ? f0 : -f0;
            a1 += ((mm.y >> bsh) & 1u) ? f1 : -f1;
            a2 += ((mm.z >> bsh) & 1u) ? f2 : -f2;
            a3 += ((mm.w >> bsh) & 1u) ? f3 : -f3;
        }
        part[kk][tid] = (a0 + a1) + (a2 + a3);
    }
    __syncthreads();
    if (tid < 128) {
        float e0 = part[0][tid] + part[0][tid + 128] + linear[NV + k0];
        float e1 = part[1][tid] + part[1][tid + 128] + linear[NV + k0 + 1];
        float2 o = make_float2(tanhf(-e0), tanhf(-e1));
        *(float2*)(out + (size_t)tid * NH + k0) = o;   // k0 even -> 8B aligned
    }
}

extern "C" void kernel_launch(void* const* d_in, const int* in_sizes, int n_in,
                              void* d_out, int out_size, void* d_ws, size_t ws_size,
                              hipStream_t stream) {
    const float* linear = (const float*)d_in[0];
    const float* quad   = (const float*)d_in[1];
    const int*   s      = (const int*)d_in[2];
    const int*   adj    = (const int*)d_in[3];
    const int*   seg    = (const int*)d_in[5];
    const int E = in_sizes[5];
    float* out = (float*)d_out;

    char* ws = (char*)d_ws;
    uint32_t* bits    = (uint32_t*)(ws);
    uint32_t* cursors = (uint32_t*)(ws + 800000);
    uint2*    recs    = (uint2*)   (ws + 960000);

    (void)hipMemsetAsync(cursors, 0, NH * NG * sizeof(uint32_t), stream);
    const int E4 = E / 4;                             // E = 1,000,000 -> /4 exact
    const int packBlocks = (NV * 4 + 255) / 256;      // 782
    const int scatBlocks = (E4 + 1023) / 1024;        // 245 (16 edges/thread)
    pack_scatter_kernel<<<packBlocks + scatBlocks, 256, 0, stream>>>(
        s, bits, (const vint4*)adj, (const vint4*)seg, (const vfloat4*)quad,
        cursors, recs, packBlocks, E4);
    field_tanh_kernel<<<313 * 8, 256, 0, stream>>>(cursors, recs, (const uint4*)bits,
                                                   linear, out);
}